// Round 11
// baseline (181.434 us; speedup 1.0000x reference)
//
#include <hip/hip_runtime.h>
#include <hip/hip_bf16.h>
#include <stdint.h>

// Problem constants (from reference)
#define NB 8
#define NT 2048
#define ND 512
#define NH 4
#define NDK 128
#define QKV_LD 1536   // row stride of qkv buffer (3*D)
#define KW 11

typedef unsigned short u16;
typedef __attribute__((ext_vector_type(4))) float f32x4;
typedef __attribute__((ext_vector_type(16))) float f32x16;
typedef __attribute__((ext_vector_type(4))) float fv4;
typedef __attribute__((ext_vector_type(8))) short s16x8;   // 8 bf16 = 4 VGPR
typedef __attribute__((ext_vector_type(4))) unsigned short u16x4;
typedef __attribute__((ext_vector_type(4))) int i32x4;

#define AS1 __attribute__((address_space(1)))
#define AS3 __attribute__((address_space(3)))

__device__ __forceinline__ u16 f2bf(float f){
  unsigned u = __float_as_uint(f);
  u += 0x7fffu + ((u >> 16) & 1u);      // RNE
  return (u16)(u >> 16);
}
__device__ __forceinline__ float bf2f(u16 h){ return __uint_as_float(((unsigned)h) << 16); }
__device__ __forceinline__ unsigned pack2bf(float a, float b){
  float2 t; t.x = a; t.y = b;
  __hip_bfloat162 h = __float22bfloat162_rn(t);   // v_cvt_pk_bf16_f32 (RNE, same as f2bf)
  return *reinterpret_cast<unsigned*>(&h);
}

// ---------------------------------------------------------------- prep: weight transposes only
// blocks [0,768): Wqkv transpose+cvt (512x1536 -> 1536x512); [768,1024): Wout (512x512)
__device__ __forceinline__ void transpose_body(
    const float* __restrict__ in, u16* __restrict__ out, int R, int C,
    int bx, int by, int tid)
{
  __shared__ float tile[32][33];
  const int cb = bx * 32, rb = by * 32;
  const int tx = tid & 31, ty = tid >> 5;   // (32,8)
  #pragma unroll
  for (int i = 0; i < 4; ++i)
    tile[ty + i*8][tx] = in[(size_t)(rb + ty + i*8) * C + cb + tx];
  __syncthreads();
  #pragma unroll
  for (int i = 0; i < 4; ++i)
    out[(size_t)(cb + ty + i*8) * R + rb + tx] = f2bf(tile[tx][ty + i*8]);
}

__global__ void prep_kernel(const float* __restrict__ Wqkv, u16* __restrict__ wqkvT,
                            const float* __restrict__ Wout, u16* __restrict__ woutT)
{
  const int bid = blockIdx.x, tid = threadIdx.x;
  if (bid < 768){
    transpose_body(Wqkv, wqkvT, 512, 1536, bid % 48, bid / 48, tid);
  } else {
    const int idx = bid - 768;               // grid (16,16)
    transpose_body(Wout, woutT, 512, 512, idx % 16, idx / 16, tid);
  }
}

// ---------------------------------------------------------------- qkv GEMM, A = f32 x (direct)
// C = A * Bt^T + bias -> bf16 qkvb; v-range blocks also write transposed V (vT).
// A staged as f32 (16KB/k-step) with rule-#21 XOR swizzle: linear LDS dest, source col
// c^(row&7); frag read picks chunks 2g^(R&7), ^1 -> 2-way banks (free), then cvt_pk->bf16.
__global__ __launch_bounds__(256, 2) void gemm_x(
    const float* __restrict__ A, const u16* __restrict__ Bt, const float* __restrict__ bias,
    u16* __restrict__ Cb, u16* __restrict__ vTout, int M, int N, int Kd)
{
  __shared__ float Asf[128 * 32];
  __shared__ u16 Bs[128 * 32];
  const int tid = threadIdx.x;
  const int m0 = blockIdx.y * 128, n0 = blockIdx.x * 128;
  const int w = tid >> 6, l = tid & 63, wr = w >> 1, wc = w & 1;
  const int r15 = l & 15, g = l >> 4;

  f32x4 acc[4][4] = {};

  const int brow = tid >> 2, bkc = tid & 3;
  const u16* Bg0 = Bt + (size_t)(n0 + brow)      * Kd + bkc * 8;
  const u16* Bg1 = Bt + (size_t)(n0 + brow + 64) * Kd + bkc * 8;
  u16* Bl0 = &Bs[(size_t)tid * 8];
  u16* Bl1 = &Bs[2048 + (size_t)tid * 8];

  for (int k0 = 0; k0 < Kd; k0 += 32){
    #pragma unroll
    for (int i = 0; i < 4; ++i){              // A: 1024 chunks of 16B (4 f32)
      const int n = i*256 + tid, row = n >> 3, c = n & 7;
      const float* gp = A + (size_t)(m0 + row) * Kd + k0 + ((c ^ (row & 7)) << 2);
      __builtin_amdgcn_global_load_lds((AS1 void*)gp, (AS3 void*)&Asf[n*4], 16, 0, 0);
    }
    __builtin_amdgcn_global_load_lds((AS1 void*)(Bg0 + k0), (AS3 void*)Bl0, 16, 0, 0);
    __builtin_amdgcn_global_load_lds((AS1 void*)(Bg1 + k0), (AS3 void*)Bl1, 16, 0, 0);
    __syncthreads();
    s16x8 af[4], bfr[4];
    #pragma unroll
    for (int m = 0; m < 4; ++m){
      const int R = wr*64 + m*16 + r15;
      const int c1 = (2*g) ^ (R & 7);
      fv4 lo  = *reinterpret_cast<const fv4*>(&Asf[R*32 + c1*4]);        // cols g*8..+3
      fv4 hi4 = *reinterpret_cast<const fv4*>(&Asf[R*32 + (c1^1)*4]);    // cols g*8+4..+7
      union { unsigned u[4]; s16x8 h; } uu;
      uu.u[0] = pack2bf(lo[0],  lo[1]);
      uu.u[1] = pack2bf(lo[2],  lo[3]);
      uu.u[2] = pack2bf(hi4[0], hi4[1]);
      uu.u[3] = pack2bf(hi4[2], hi4[3]);
      af[m] = uu.h;
    }
    #pragma unroll
    for (int n = 0; n < 4; ++n)
      bfr[n] = *reinterpret_cast<const s16x8*>(&Bs[(wc*64 + n*16 + r15) * 32 + g*8]);
    #pragma unroll
    for (int m = 0; m < 4; ++m){
      #pragma unroll
      for (int n = 0; n < 4; ++n)
        acc[m][n] = __builtin_amdgcn_mfma_f32_16x16x32_bf16(af[m], bfr[n], acc[m][n], 0, 0, 0);
    }
    __syncthreads();
  }

  const bool vrange = (n0 >= 2*ND);            // block-uniform (128-aligned ranges)
  #pragma unroll
  for (int m = 0; m < 4; ++m){
    const int gr0 = m0 + wr*64 + m*16 + g*4;
    #pragma unroll
    for (int n = 0; n < 4; ++n){
      const int gc = n0 + wc*64 + n*16 + r15;
      const float bv = bias[gc];
      u16x4 pk;
      #pragma unroll
      for (int j = 0; j < 4; ++j){
        const u16 hv = f2bf(acc[m][n][j] + bv);
        Cb[(size_t)(gr0 + j) * N + gc] = hv;
        pk[j] = hv;
      }
      if (vrange){                              // also write transposed V
        const int d  = gc - 2*ND;
        const int bh = (gr0 >> 11) * NH + (d >> 7);
        const int dk = d & 127, t = gr0 & 2047;
        *reinterpret_cast<u16x4*>(&vTout[((size_t)bh * NDK + dk) * NT + t]) = pk;
      }
    }
  }
}

// ---------------------------------------------------------------- bf16 GEMM  C = A * Bt^T + bias
// EPI==1 (used for out GEMM): C -> f32 out with FUSED FSMN epilogue.
template<int EPI>
__global__ __launch_bounds__(256, 2) void gemm_bt(
    const u16* __restrict__ A, const u16* __restrict__ Bt, const float* __restrict__ bias,
    u16* __restrict__ Cb, float* __restrict__ Cf, u16* __restrict__ vTout,
    const u16* __restrict__ qkvb, const float* __restrict__ mask,
    const float* __restrict__ fsmn_w,
    int M, int N, int Kd)
{
  __shared__ u16 As[128 * 32];
  __shared__ u16 Bs[128 * 32];
  const int tid = threadIdx.x;
  const int m0 = blockIdx.y * 128, n0 = blockIdx.x * 128;
  const int w = tid >> 6, l = tid & 63, wr = w >> 1, wc = w & 1;
  const int r15 = l & 15, g = l >> 4;

  f32x4 acc[4][4] = {};

  const int row = tid >> 2, kc = tid & 3;       // chunk -> (row, 16B-chunk-in-row)
  const u16* Ag0 = A  + (size_t)(m0 + row)      * Kd + kc * 8;
  const u16* Ag1 = A  + (size_t)(m0 + row + 64) * Kd + kc * 8;
  const u16* Bg0 = Bt + (size_t)(n0 + row)      * Kd + kc * 8;
  const u16* Bg1 = Bt + (size_t)(n0 + row + 64) * Kd + kc * 8;
  u16* Al0 = &As[(size_t)tid * 8];
  u16* Al1 = &As[2048 + (size_t)tid * 8];
  u16* Bl0 = &Bs[(size_t)tid * 8];
  u16* Bl1 = &Bs[2048 + (size_t)tid * 8];

  for (int k0 = 0; k0 < Kd; k0 += 32){
    __builtin_amdgcn_global_load_lds((AS1 void*)(Ag0 + k0), (AS3 void*)Al0, 16, 0, 0);
    __builtin_amdgcn_global_load_lds((AS1 void*)(Ag1 + k0), (AS3 void*)Al1, 16, 0, 0);
    __builtin_amdgcn_global_load_lds((AS1 void*)(Bg0 + k0), (AS3 void*)Bl0, 16, 0, 0);
    __builtin_amdgcn_global_load_lds((AS1 void*)(Bg1 + k0), (AS3 void*)Bl1, 16, 0, 0);
    __syncthreads();
    s16x8 af[4], bfr[4];
    #pragma unroll
    for (int m = 0; m < 4; ++m)
      af[m] = *reinterpret_cast<const s16x8*>(&As[(wr*64 + m*16 + r15) * 32 + g*8]);
    #pragma unroll
    for (int n = 0; n < 4; ++n)
      bfr[n] = *reinterpret_cast<const s16x8*>(&Bs[(wc*64 + n*16 + r15) * 32 + g*8]);
    #pragma unroll
    for (int m = 0; m < 4; ++m){
      #pragma unroll
      for (int n = 0; n < 4; ++n)
        acc[m][n] = __builtin_amdgcn_mfma_f32_16x16x32_bf16(af[m], bfr[n], acc[m][n], 0, 0, 0);
    }
    __syncthreads();
  }

  if (EPI == 0){
    #pragma unroll
    for (int m = 0; m < 4; ++m){
      const int gr0 = m0 + wr*64 + m*16 + g*4;
      #pragma unroll
      for (int n = 0; n < 4; ++n){
        const int gc = n0 + wc*64 + n*16 + r15;
        const float bv = bias[gc];
        #pragma unroll
        for (int j = 0; j < 4; ++j)
          Cb[(size_t)(gr0 + j) * N + gc] = f2bf(acc[m][n][j] + bv);
      }
    }
  } else {
    // fused FSMN epilogue
    float wv[4][KW];
    #pragma unroll
    for (int n = 0; n < 4; ++n){
      const int gc = n0 + wc*64 + n*16 + r15;
      #pragma unroll
      for (int i = 0; i < KW; ++i) wv[n][i] = fsmn_w[gc*KW + i];
    }
    #pragma unroll
    for (int m = 0; m < 4; ++m){
      const int gr0 = m0 + wr*64 + m*16 + g*4;
      const int bb = gr0 >> 11, t0 = gr0 & 2047;
      const float* mb = mask + (size_t)bb * NT;
      float mk[14];
      #pragma unroll
      for (int i = 0; i < 14; ++i){
        const int tau = t0 - 5 + i;
        mk[i] = ((unsigned)tau < (unsigned)NT) ? mb[tau] : 0.f;
      }
      #pragma unroll
      for (int n = 0; n < 4; ++n){
        const int gc = n0 + wc*64 + n*16 + r15;
        const float bv = bias[gc];
        const u16* vb = qkvb + (size_t)bb * NT * QKV_LD + 2*ND + gc;
        float vmv[14];
        #pragma unroll
        for (int i = 0; i < 14; ++i){
          const ptrdiff_t tau = t0 - 5 + i;
          vmv[i] = mk[i] * bf2f(vb[tau * QKV_LD]);   // mk=0 zeroes OOB taps
        }
        #pragma unroll
        for (int j = 0; j < 4; ++j){
          float conv = vmv[5 + j];                    // vm[t] residual term
          #pragma unroll
          for (int i = 0; i < KW; ++i) conv = fmaf(wv[n][i], vmv[j + i], conv);
          Cf[(size_t)(gr0 + j) * N + gc] = acc[m][n][j] + bv + mk[5 + j] * conv;
        }
      }
    }
  }
}

// ---------------------------------------------------------------- flash attention (4-wave, 32x32x16)
// R8 structure (verified 110us): 256 thr = 4 waves x 32 q-rows; grid 512 = 2 independent
// blocks/CU so one block's softmax/barrier-drain overlaps the other's MFMA (m114).
// Swapped QK^T: mfma(A=K, B=Q) -> lane owns ONE q-row, 32 scores in D regs.
// P->A-frag via 2x v_permlane32_swap_b32 per k-step. Single score set.
// DO NOT raise launch_bounds 2nd arg (R9: (256,3) -> 84 VGPR + scratch spill, 2.2x slower).
#define ATT_MFMA(a, bb, c) __builtin_amdgcn_mfma_f32_32x32x16_bf16(a, bb, c, 0, 0, 0)
#define C1F 0.12751741567f   /* (1/sqrt(128)) * log2(e) */

__global__ __launch_bounds__(256, 2) void attn_kernel(
    const u16* __restrict__ qkvb, const u16* __restrict__ vT,
    const float* __restrict__ mask, u16* __restrict__ ctxb)
{
  __shared__ u16 Ks[2][64 * 128];   // [key][dk], swizzled 16B chunks
  __shared__ u16 Vs[2][128 * 64];   // [dk][key], swizzled 16B chunks
  const int tid = threadIdx.x;
  const int w = tid >> 6, l = tid & 63, l31 = l & 31, hi = l >> 5;

  // XCD-bijective remap: all 16 q-blocks of one bh land on one XCD (K/V L2 locality)
  const int lin = blockIdx.x + blockIdx.y * 8;    // grid = (8, 64)
  const int xcd = lin & 7, jj = lin >> 3;         // jj 0..63
  const int bh = xcd * 4 + (jj & 3), qblk = jj >> 2;
  const int b = bh >> 2, h = bh & 3;
  const int q0 = qblk * 128;

  const u16* qptr = qkvb + (size_t)b * NT * QKV_LD + h * NDK;
  const u16* kb   = qptr + ND;
  const u16* vtb  = vT + (size_t)bh * NDK * NT;
  const float* mkp = mask + (size_t)b * NT;

  // Q in registers (B-operand): lane holds Q[q0+w*32+l31][s*16 + hi*8 .. +7]
  s16x8 qf[8];
  {
    const u16* qrow = qptr + (size_t)(q0 + w*32 + l31) * QKV_LD;
    #pragma unroll
    for (int s = 0; s < 8; ++s)
      qf[s] = *reinterpret_cast<const s16x8*>(qrow + s*16 + hi*8);
  }

  float mrun = -1e30f, lrun = 0.f;
  f32x16 o0 = {}, o1 = {}, o2 = {}, o3 = {};

  // K chunk c: key = c>>4, slot = c&15 (256B contiguous per key row, source XOR-swizzled).
  // V chunk c: dk = c>>3, kslot = c&7 (128B contiguous per dk row).
#define STAGE(buf, kvo) do { \
    _Pragma("unroll") \
    for (int i_ = 0; i_ < 4; ++i_){ \
      const int n_ = i_*256 + tid, kr_ = n_ >> 4, c_ = n_ & 15; \
      const u16* gp_ = kb + (size_t)((kvo) + kr_) * QKV_LD + ((c_ ^ (kr_ & 7)) << 3); \
      __builtin_amdgcn_global_load_lds((AS1 void*)gp_, (AS3 void*)&Ks[buf][n_*8], 16, 0, 0); \
    } \
    _Pragma("unroll") \
    for (int i_ = 0; i_ < 4; ++i_){ \
      const int n_ = i_*256 + tid, dr_ = n_ >> 3, kc_ = n_ & 7; \
      const u16* gp_ = vtb + (size_t)dr_ * NT + (kvo) + ((kc_ ^ (dr_ & 7)) << 3); \
      __builtin_amdgcn_global_load_lds((AS1 void*)gp_, (AS3 void*)&Vs[buf][n_*8], 16, 0, 0); \
    } \
  } while(0)

  STAGE(0, 0);
  __syncthreads();
  int cur = 0;

  for (int t = 0; t < NT/64; ++t){
    const int kv0 = t * 64;
    if (t + 1 < NT/64) STAGE(cur ^ 1, kv0 + 64);

    // mask for this tile: lane's k-locals are b32*32 + r8*8 + 4*hi + j
    fv4 mA[4], mB[4];
    #pragma unroll
    for (int r8 = 0; r8 < 4; ++r8){
      mA[r8] = *reinterpret_cast<const fv4*>(&mkp[kv0      + r8*8 + hi*4]);
      mB[r8] = *reinterpret_cast<const fv4*>(&mkp[kv0 + 32 + r8*8 + hi*4]);
    }

    // S^T = K Q^T: d0 keys kv0+0..31, d1 keys kv0+32..63; lane owns q-col l31
    f32x16 d0 = {}, d1 = {};
    __builtin_amdgcn_s_setprio(1);
    #pragma unroll
    for (int s = 0; s < 8; ++s){
      const int cg = s*2 + hi;
      s16x8 kf0 = *reinterpret_cast<const s16x8*>(
          &Ks[cur][ l31*128      + ((cg ^ (l31 & 7)) << 3) ]);
      s16x8 kf1 = *reinterpret_cast<const s16x8*>(
          &Ks[cur][ (32+l31)*128 + ((cg ^ (l31 & 7)) << 3) ]);
      d0 = ATT_MFMA(kf0, qf[s], d0);
      d1 = ATT_MFMA(kf1, qf[s], d1);
    }
    __builtin_amdgcn_s_setprio(0);

    // row max over raw scores: max3-friendly tree, then cross-half
    float mx0 = fmaxf(d0[0], d0[1]), mx1 = fmaxf(d0[2], d0[3]);
    float mx2 = fmaxf(d1[0], d1[1]), mx3 = fmaxf(d1[2], d1[3]);
    #pragma unroll
    for (int r = 4; r < 16; r += 4){
      mx0 = fmaxf(mx0, fmaxf(d0[r],   d0[r+1]));
      mx1 = fmaxf(mx1, fmaxf(d0[r+2], d0[r+3]));
      mx2 = fmaxf(mx2, fmaxf(d1[r],   d1[r+1]));
      mx3 = fmaxf(mx3, fmaxf(d1[r+2], d1[r+3]));
    }
    float tmx = fmaxf(fmaxf(mx0, mx1), fmaxf(mx2, mx3));
    tmx = fmaxf(tmx, __shfl_xor(tmx, 32));

    // T13 defer-max (raw-score threshold 64 ~ 8 nats)
    if (!__all(tmx <= mrun + 64.f)){
      const float mn = fmaxf(mrun, tmx);
      const float corr = __builtin_amdgcn_exp2f((mrun - mn) * C1F);
      mrun = mn; lrun *= corr;
      #pragma unroll
      for (int r = 0; r < 16; ++r){
        const int qs = (r & 3) + 8*(r >> 2) + 4*hi;
        const float cq = __shfl(corr, qs);
        o0[r] *= cq; o1[r] *= cq; o2[r] *= cq; o3[r] *= cq;
      }
    }

    // p = exp2(fma(s, c1, -m*c1)) * mask; in-place into d0/d1; accumulate l
    const float mm = mrun * C1F;
    float ts = 0.f;
    #pragma unroll
    for (int r = 0; r < 16; ++r){
      const int r8 = r >> 2, j = r & 3;
      const float p0 = __builtin_amdgcn_exp2f(fmaf(d0[r], C1F, -mm)) * mA[r8][j];
      const float p1 = __builtin_amdgcn_exp2f(fmaf(d1[r], C1F, -mm)) * mB[r8][j];
      d0[r] = p0; d1[r] = p1; ts += p0 + p1;
    }
    ts += __shfl_xor(ts, 32);
    lrun += ts;

    // pack p -> bf16 pairs
    unsigned pku[2][4][2];
    #pragma unroll
    for (int r8 = 0; r8 < 4; ++r8){
      pku[0][r8][0] = pack2bf(d0[4*r8+0], d0[4*r8+1]);
      pku[0][r8][1] = pack2bf(d0[4*r8+2], d0[4*r8+3]);
      pku[1][r8][0] = pack2bf(d1[4*r8+0], d1[4*r8+1]);
      pku[1][r8][1] = pack2bf(d1[4*r8+2], d1[4*r8+3]);
    }

    // PV: per k-step build A-frag with 2 permlane32_swap, then 4 dk-blocks
    #pragma unroll
    for (int ks = 0; ks < 4; ++ks){
      const int bb = ks >> 1, rlo = (ks & 1) * 2;
      int u0 = (int)pku[bb][rlo][0],   u1 = (int)pku[bb][rlo][1];
      int v0 = (int)pku[bb][rlo+1][0], v1 = (int)pku[bb][rlo+1][1];
      asm("v_permlane32_swap_b32 %0, %1" : "+v"(u0), "+v"(v0));
      asm("v_permlane32_swap_b32 %0, %1" : "+v"(u1), "+v"(v1));
      union { i32x4 i; s16x8 hv; } pu;
      pu.i[0] = u0; pu.i[1] = u1; pu.i[2] = v0; pu.i[3] = v1;
      const int cg = ks*2 + hi;
      s16x8 vf0 = *reinterpret_cast<const s16x8*>(&Vs[cur][ (l31     )*64 + ((cg ^ (l31 & 7)) << 3) ]);
      s16x8 vf1 = *reinterpret_cast<const s16x8*>(&Vs[cur][ (32 + l31)*64 + ((cg ^ (l31 & 7)) << 3) ]);
      s16x8 vf2 = *reinterpret_cast<const s16x8*>(&Vs[cur][ (64 + l31)*64 + ((cg ^ (l31 & 7)) << 3) ]);
      s16x8 vf3 = *reinterpret_cast<const s16x8*>(&Vs[cur][ (96 + l31)*64 + ((cg ^ (l31 & 7)) << 3) ]);
      __builtin_amdgcn_s_setprio(1);
      o0 = ATT_MFMA(pu.hv, vf0, o0);
      o1 = ATT_MFMA(pu.hv, vf1, o1);
      o2 = ATT_MFMA(pu.hv, vf2, o2);
      o3 = ATT_MFMA(pu.hv, vf3, o3);
      __builtin_amdgcn_s_setprio(0);
    }

    __syncthreads();
    cur ^= 1;
  }

  // epilogue: O[q][dk] regs: col dk = dkblk*32 + l31, row q = (r&3)+8*(r>>2)+4*hi
  #pragma unroll
  for (int r = 0; r < 16; ++r){
    const int qs = (r & 3) + 8*(r >> 2) + 4*hi;
    const float lr = __shfl(lrun, qs);
    const float rl = (lr > 0.f) ? (1.f / lr) : 0.f;
    const int row = q0 + w*32 + qs;
    u16* cp = ctxb + (size_t)(b*NT + row) * ND + h*NDK + l31;
    cp[0]  = f2bf(o0[r] * rl);
    cp[32] = f2bf(o1[r] * rl);
    cp[64] = f2bf(o2[r] * rl);
    cp[96] = f2bf(o3[r] * rl);
  }
#undef STAGE
}

// ---------------------------------------------------------------- launcher
extern "C" void kernel_launch(void* const* d_in, const int* in_sizes, int n_in,
                              void* d_out, int out_size, void* d_ws, size_t ws_size,
                              hipStream_t stream) {
  const float* x      = (const float*)d_in[0];
  const float* mask   = (const float*)d_in[1];
  const float* Wqkv   = (const float*)d_in[2];
  const float* bqkv   = (const float*)d_in[3];
  const float* Wout   = (const float*)d_in[4];
  const float* bout   = (const float*)d_in[5];
  const float* fsmn_w = (const float*)d_in[6];
  float* out = (float*)d_out;

  // workspace layout (bytes), total ~86 MB (xb eliminated: gemm_x reads f32 x directly)
  char* ws = (char*)d_ws;
  u16* wqkvT = (u16*)ws;                         //  1,572,864
  u16* woutT = (u16*)(ws + 1572864);             //    524,288
  u16* qkvb  = (u16*)(ws + 2097152);             // 50,331,648
  u16* ctxb  = (u16*)(ws + 52428800);            // 16,777,216
  u16* vT    = (u16*)(ws + 69206016);            // 16,777,216  -> ends 85,983,232

  prep_kernel<<<1024, 256, 0, stream>>>(Wqkv, wqkvT, Wout, woutT);
  gemm_x<<<dim3(1536/128, 16384/128), 256, 0, stream>>>(
      x, wqkvT, bqkv, qkvb, vT, NB*NT, QKV_LD, ND);
  attn_kernel<<<dim3(8, 64), 256, 0, stream>>>(qkvb, vT, mask, ctxb);
  gemm_bt<1><<<dim3(512/128, 16384/128), 256, 0, stream>>>(
      ctxb, woutT, bout, nullptr, out, nullptr, qkvb, mask, fsmn_w, NB*NT, ND, ND);
}

// Round 12
// 174.225 us; speedup vs baseline: 1.0414x; 1.0414x over previous
//
#include <hip/hip_runtime.h>
#include <hip/hip_bf16.h>
#include <stdint.h>

// Problem constants (from reference)
#define NB 8
#define NT 2048
#define ND 512
#define NH 4
#define NDK 128
#define QKV_LD 1536   // row stride of qkv buffer (3*D)
#define KW 11

typedef unsigned short u16;
typedef __attribute__((ext_vector_type(4))) float f32x4;
typedef __attribute__((ext_vector_type(16))) float f32x16;
typedef __attribute__((ext_vector_type(4))) float fv4;
typedef __attribute__((ext_vector_type(8))) short s16x8;   // 8 bf16 = 4 VGPR
typedef __attribute__((ext_vector_type(4))) unsigned short u16x4;
typedef __attribute__((ext_vector_type(4))) int i32x4;

#define AS1 __attribute__((address_space(1)))
#define AS3 __attribute__((address_space(3)))

__device__ __forceinline__ u16 f2bf(float f){
  unsigned u = __float_as_uint(f);
  u += 0x7fffu + ((u >> 16) & 1u);      // RNE
  return (u16)(u >> 16);
}
__device__ __forceinline__ float bf2f(u16 h){ return __uint_as_float(((unsigned)h) << 16); }
__device__ __forceinline__ unsigned pack2bf(float a, float b){
  float2 t; t.x = a; t.y = b;
  __hip_bfloat162 h = __float22bfloat162_rn(t);
  return *reinterpret_cast<unsigned*>(&h);
}

// ---------------------------------------------------------------- fused prep:
// blocks [0,1024): x -> bf16 (grid-stride)
// blocks [1024,1792): Wqkv transpose+cvt (512x1536 -> 1536x512)
// blocks [1792,2048): Wout transpose+cvt (512x512)
__device__ __forceinline__ void transpose_body(
    const float* __restrict__ in, u16* __restrict__ out, int R, int C,
    int bx, int by, int tid)
{
  __shared__ float tile[32][33];
  const int cb = bx * 32, rb = by * 32;
  const int tx = tid & 31, ty = tid >> 5;   // (32,8)
  #pragma unroll
  for (int i = 0; i < 4; ++i)
    tile[ty + i*8][tx] = in[(size_t)(rb + ty + i*8) * C + cb + tx];
  __syncthreads();
  #pragma unroll
  for (int i = 0; i < 4; ++i)
    out[(size_t)(cb + ty + i*8) * R + rb + tx] = f2bf(tile[tx][ty + i*8]);
}

__global__ void prep_kernel(const float* __restrict__ x, u16* __restrict__ xb,
                            const float* __restrict__ Wqkv, u16* __restrict__ wqkvT,
                            const float* __restrict__ Wout, u16* __restrict__ woutT)
{
  const int bid = blockIdx.x, tid = threadIdx.x;
  if (bid < 1024){
    const int n4 = (NB*NT*ND)/4;
    for (int i = bid*256 + tid; i < n4; i += 1024*256){
      float4 v = reinterpret_cast<const float4*>(x)[i];
      u16x4 o = { f2bf(v.x), f2bf(v.y), f2bf(v.z), f2bf(v.w) };
      reinterpret_cast<u16x4*>(xb)[i] = o;
    }
  } else if (bid < 1792){
    const int idx = bid - 1024;              // grid (48,16)
    transpose_body(Wqkv, wqkvT, 512, 1536, idx % 48, idx / 48, tid);
  } else {
    const int idx = bid - 1792;              // grid (16,16)
    transpose_body(Wout, woutT, 512, 512, idx % 16, idx / 16, tid);
  }
}

// ---------------------------------------------------------------- bf16 GEMM  C = A * Bt^T + bias
// EPI==0: C -> bf16 buffer; blocks in the v-column range (n0 >= 2*ND) ALSO write their
//         tile transposed into vT (j=0..3 are 4 consecutive t -> one 8B u16x4 store).
// EPI==1: C -> f32 out with FUSED FSMN: out = acc + bias + m[t]*(vm[t]+sum w[i]*vm[t-5+i]),
//         vm[tau] = m[tau]*v[tau][gc] read directly from qkvb (L2-resident). OOB taps are
//         zeroed via mk=0 (unguarded loads stay inside workspace -> finite garbage * 0).
template<int EPI>
__global__ __launch_bounds__(256, 2) void gemm_bt(
    const u16* __restrict__ A, const u16* __restrict__ Bt, const float* __restrict__ bias,
    u16* __restrict__ Cb, float* __restrict__ Cf, u16* __restrict__ vTout,
    const u16* __restrict__ qkvb, const float* __restrict__ mask,
    const float* __restrict__ fsmn_w,
    int M, int N, int Kd)
{
  __shared__ u16 As[128 * 32];
  __shared__ u16 Bs[128 * 32];
  const int tid = threadIdx.x;
  const int m0 = blockIdx.y * 128, n0 = blockIdx.x * 128;
  const int w = tid >> 6, l = tid & 63, wr = w >> 1, wc = w & 1;
  const int r15 = l & 15, g = l >> 4;

  f32x4 acc[4][4] = {};

  const int row = tid >> 2, kc = tid & 3;       // chunk -> (row, 16B-chunk-in-row)
  const u16* Ag0 = A  + (size_t)(m0 + row)      * Kd + kc * 8;
  const u16* Ag1 = A  + (size_t)(m0 + row + 64) * Kd + kc * 8;
  const u16* Bg0 = Bt + (size_t)(n0 + row)      * Kd + kc * 8;
  const u16* Bg1 = Bt + (size_t)(n0 + row + 64) * Kd + kc * 8;
  u16* Al0 = &As[(size_t)tid * 8];
  u16* Al1 = &As[2048 + (size_t)tid * 8];
  u16* Bl0 = &Bs[(size_t)tid * 8];
  u16* Bl1 = &Bs[2048 + (size_t)tid * 8];

  for (int k0 = 0; k0 < Kd; k0 += 32){
    __builtin_amdgcn_global_load_lds((AS1 void*)(Ag0 + k0), (AS3 void*)Al0, 16, 0, 0);
    __builtin_amdgcn_global_load_lds((AS1 void*)(Ag1 + k0), (AS3 void*)Al1, 16, 0, 0);
    __builtin_amdgcn_global_load_lds((AS1 void*)(Bg0 + k0), (AS3 void*)Bl0, 16, 0, 0);
    __builtin_amdgcn_global_load_lds((AS1 void*)(Bg1 + k0), (AS3 void*)Bl1, 16, 0, 0);
    __syncthreads();
    s16x8 af[4], bfr[4];
    #pragma unroll
    for (int m = 0; m < 4; ++m)
      af[m] = *reinterpret_cast<const s16x8*>(&As[(wr*64 + m*16 + r15) * 32 + g*8]);
    #pragma unroll
    for (int n = 0; n < 4; ++n)
      bfr[n] = *reinterpret_cast<const s16x8*>(&Bs[(wc*64 + n*16 + r15) * 32 + g*8]);
    #pragma unroll
    for (int m = 0; m < 4; ++m){
      #pragma unroll
      for (int n = 0; n < 4; ++n)
        acc[m][n] = __builtin_amdgcn_mfma_f32_16x16x32_bf16(af[m], bfr[n], acc[m][n], 0, 0, 0);
    }
    __syncthreads();
  }

  if (EPI == 0){
    const bool vrange = (n0 >= 2*ND);            // block-uniform (128-aligned ranges)
    #pragma unroll
    for (int m = 0; m < 4; ++m){
      const int gr0 = m0 + wr*64 + m*16 + g*4;
      #pragma unroll
      for (int n = 0; n < 4; ++n){
        const int gc = n0 + wc*64 + n*16 + r15;
        const float bv = bias[gc];
        u16x4 pk;
        #pragma unroll
        for (int j = 0; j < 4; ++j){
          const u16 hv = f2bf(acc[m][n][j] + bv);
          Cb[(size_t)(gr0 + j) * N + gc] = hv;
          pk[j] = hv;
        }
        if (vrange){                              // also write transposed V
          const int d  = gc - 2*ND;
          const int bh = (gr0 >> 11) * NH + (d >> 7);
          const int dk = d & 127, t = gr0 & 2047;
          *reinterpret_cast<u16x4*>(&vTout[((size_t)bh * NDK + dk) * NT + t]) = pk;
        }
      }
    }
  } else {
    // fused FSMN epilogue
    float wv[4][KW];
    #pragma unroll
    for (int n = 0; n < 4; ++n){
      const int gc = n0 + wc*64 + n*16 + r15;
      #pragma unroll
      for (int i = 0; i < KW; ++i) wv[n][i] = fsmn_w[gc*KW + i];
    }
    #pragma unroll
    for (int m = 0; m < 4; ++m){
      const int gr0 = m0 + wr*64 + m*16 + g*4;
      const int bb = gr0 >> 11, t0 = gr0 & 2047;
      const float* mb = mask + (size_t)bb * NT;
      float mk[14];
      #pragma unroll
      for (int i = 0; i < 14; ++i){
        const int tau = t0 - 5 + i;
        mk[i] = ((unsigned)tau < (unsigned)NT) ? mb[tau] : 0.f;
      }
      #pragma unroll
      for (int n = 0; n < 4; ++n){
        const int gc = n0 + wc*64 + n*16 + r15;
        const float bv = bias[gc];
        const u16* vb = qkvb + (size_t)bb * NT * QKV_LD + 2*ND + gc;
        float vmv[14];
        #pragma unroll
        for (int i = 0; i < 14; ++i){
          const ptrdiff_t tau = t0 - 5 + i;
          vmv[i] = mk[i] * bf2f(vb[tau * QKV_LD]);   // mk=0 zeroes OOB taps
        }
        #pragma unroll
        for (int j = 0; j < 4; ++j){
          float conv = vmv[5 + j];                    // vm[t] residual term
          #pragma unroll
          for (int i = 0; i < KW; ++i) conv = fmaf(wv[n][i], vmv[j + i], conv);
          Cf[(size_t)(gr0 + j) * N + gc] = acc[m][n][j] + bv + mk[5 + j] * conv;
        }
      }
    }
  }
}

// ---------------------------------------------------------------- flash attention (4-wave, 32x32x16)
// R8 structure + HALF-SPLIT online softmax: process the tile's two 32-key halves as
// sequential online-softmax updates. softmax(d1) VALU overlaps PV(d0)'s MFMA pipe
// (independent, same wave -> dual-pipe ILP). Mathematically exact (== two 32-key tiles).
// Swapped QK^T: mfma(A=K, B=Q) -> lane owns ONE q-row, 32 scores in D regs.
// P->A-frag via 2x v_permlane32_swap_b32 per k-step. QK loop keeps d0/d1 interleave.
// DO NOT raise launch_bounds 2nd arg (R9: (256,3) -> 84 VGPR + scratch spill, 2.2x slower).
#define ATT_MFMA(a, bb, c) __builtin_amdgcn_mfma_f32_32x32x16_bf16(a, bb, c, 0, 0, 0)
#define C1F 0.12751741567f   /* (1/sqrt(128)) * log2(e) */

__device__ __forceinline__ void half_update(
    f32x16& d, const fv4* mH, const u16* vsb, const int cg0, const int cg1,
    float& mrun, float& lrun, f32x16& o0, f32x16& o1, f32x16& o2, f32x16& o3,
    const int l31, const int hi)
{
  // row max over this half's raw scores
  float mx0 = fmaxf(d[0], d[1]), mx1 = fmaxf(d[2], d[3]);
  #pragma unroll
  for (int r = 4; r < 16; r += 4){
    mx0 = fmaxf(mx0, fmaxf(d[r],   d[r+1]));
    mx1 = fmaxf(mx1, fmaxf(d[r+2], d[r+3]));
  }
  float tmx = fmaxf(mx0, mx1);
  tmx = fmaxf(tmx, __shfl_xor(tmx, 32));

  // T13 defer-max (raw-score threshold 64 ~ 8 nats)
  if (!__all(tmx <= mrun + 64.f)){
    const float mn = fmaxf(mrun, tmx);
    const float corr = __builtin_amdgcn_exp2f((mrun - mn) * C1F);
    mrun = mn; lrun *= corr;
    #pragma unroll
    for (int r = 0; r < 16; ++r){
      const int qs = (r & 3) + 8*(r >> 2) + 4*hi;
      const float cq = __shfl(corr, qs);
      o0[r] *= cq; o1[r] *= cq; o2[r] *= cq; o3[r] *= cq;
    }
  }

  // p = exp2(fma(s, c1, -m*c1)) * mask; accumulate l
  const float mm = mrun * C1F;
  float ts = 0.f;
  #pragma unroll
  for (int r = 0; r < 16; ++r){
    const float p = __builtin_amdgcn_exp2f(fmaf(d[r], C1F, -mm)) * mH[r >> 2][r & 3];
    d[r] = p; ts += p;
  }
  ts += __shfl_xor(ts, 32);
  lrun += ts;

  // pack p -> bf16 pairs
  unsigned pk[4][2];
  #pragma unroll
  for (int r8 = 0; r8 < 4; ++r8){
    pk[r8][0] = pack2bf(d[4*r8+0], d[4*r8+1]);
    pk[r8][1] = pack2bf(d[4*r8+2], d[4*r8+3]);
  }
  // PV: 2 k-steps; per step build A-frag with 2 permlane32_swap, then 4 dk-blocks
  #pragma unroll
  for (int ks2 = 0; ks2 < 2; ++ks2){
    const int rlo = ks2 * 2;
    int u0 = (int)pk[rlo][0],   u1 = (int)pk[rlo][1];
    int v0 = (int)pk[rlo+1][0], v1 = (int)pk[rlo+1][1];
    asm("v_permlane32_swap_b32 %0, %1" : "+v"(u0), "+v"(v0));
    asm("v_permlane32_swap_b32 %0, %1" : "+v"(u1), "+v"(v1));
    union { i32x4 i; s16x8 hv; } pu;
    pu.i[0] = u0; pu.i[1] = u1; pu.i[2] = v0; pu.i[3] = v1;
    const int cg = (ks2 == 0) ? cg0 : cg1;
    s16x8 vf0 = *reinterpret_cast<const s16x8*>(&vsb[ (l31     )*64 + ((cg ^ (l31 & 7)) << 3) ]);
    s16x8 vf1 = *reinterpret_cast<const s16x8*>(&vsb[ (32 + l31)*64 + ((cg ^ (l31 & 7)) << 3) ]);
    s16x8 vf2 = *reinterpret_cast<const s16x8*>(&vsb[ (64 + l31)*64 + ((cg ^ (l31 & 7)) << 3) ]);
    s16x8 vf3 = *reinterpret_cast<const s16x8*>(&vsb[ (96 + l31)*64 + ((cg ^ (l31 & 7)) << 3) ]);
    __builtin_amdgcn_s_setprio(1);
    o0 = ATT_MFMA(pu.hv, vf0, o0);
    o1 = ATT_MFMA(pu.hv, vf1, o1);
    o2 = ATT_MFMA(pu.hv, vf2, o2);
    o3 = ATT_MFMA(pu.hv, vf3, o3);
    __builtin_amdgcn_s_setprio(0);
  }
}

__global__ __launch_bounds__(256, 2) void attn_kernel(
    const u16* __restrict__ qkvb, const u16* __restrict__ vT,
    const float* __restrict__ mask, u16* __restrict__ ctxb)
{
  __shared__ u16 Ks[2][64 * 128];   // [key][dk], swizzled 16B chunks
  __shared__ u16 Vs[2][128 * 64];   // [dk][key], swizzled 16B chunks
  const int tid = threadIdx.x;
  const int w = tid >> 6, l = tid & 63, l31 = l & 31, hi = l >> 5;

  // XCD-bijective remap: all 16 q-blocks of one bh land on one XCD (K/V L2 locality)
  const int lin = blockIdx.x + blockIdx.y * 8;    // grid = (8, 64)
  const int xcd = lin & 7, jj = lin >> 3;         // jj 0..63
  const int bh = xcd * 4 + (jj & 3), qblk = jj >> 2;
  const int b = bh >> 2, h = bh & 3;
  const int q0 = qblk * 128;

  const u16* qptr = qkvb + (size_t)b * NT * QKV_LD + h * NDK;
  const u16* kb   = qptr + ND;
  const u16* vtb  = vT + (size_t)bh * NDK * NT;
  const float* mkp = mask + (size_t)b * NT;

  // Q in registers (B-operand): lane holds Q[q0+w*32+l31][s*16 + hi*8 .. +7]
  s16x8 qf[8];
  {
    const u16* qrow = qptr + (size_t)(q0 + w*32 + l31) * QKV_LD;
    #pragma unroll
    for (int s = 0; s < 8; ++s)
      qf[s] = *reinterpret_cast<const s16x8*>(qrow + s*16 + hi*8);
  }

  float mrun = -1e30f, lrun = 0.f;
  f32x16 o0 = {}, o1 = {}, o2 = {}, o3 = {};

  // K chunk c: key = c>>4, slot = c&15 (256B contiguous per key row, source XOR-swizzled).
  // V chunk c: dk = c>>3, kslot = c&7 (128B contiguous per dk row).
#define STAGE(buf, kvo) do { \
    _Pragma("unroll") \
    for (int i_ = 0; i_ < 4; ++i_){ \
      const int n_ = i_*256 + tid, kr_ = n_ >> 4, c_ = n_ & 15; \
      const u16* gp_ = kb + (size_t)((kvo) + kr_) * QKV_LD + ((c_ ^ (kr_ & 7)) << 3); \
      __builtin_amdgcn_global_load_lds((AS1 void*)gp_, (AS3 void*)&Ks[buf][n_*8], 16, 0, 0); \
    } \
    _Pragma("unroll") \
    for (int i_ = 0; i_ < 4; ++i_){ \
      const int n_ = i_*256 + tid, dr_ = n_ >> 3, kc_ = n_ & 7; \
      const u16* gp_ = vtb + (size_t)dr_ * NT + (kvo) + ((kc_ ^ (dr_ & 7)) << 3); \
      __builtin_amdgcn_global_load_lds((AS1 void*)gp_, (AS3 void*)&Vs[buf][n_*8], 16, 0, 0); \
    } \
  } while(0)

  STAGE(0, 0);
  __syncthreads();
  int cur = 0;

  for (int t = 0; t < NT/64; ++t){
    const int kv0 = t * 64;
    if (t + 1 < NT/64) STAGE(cur ^ 1, kv0 + 64);

    // mask for this tile: lane's k-locals are b32*32 + r8*8 + 4*hi + j
    fv4 mA[4], mB[4];
    #pragma unroll
    for (int r8 = 0; r8 < 4; ++r8){
      mA[r8] = *reinterpret_cast<const fv4*>(&mkp[kv0      + r8*8 + hi*4]);
      mB[r8] = *reinterpret_cast<const fv4*>(&mkp[kv0 + 32 + r8*8 + hi*4]);
    }

    // S^T = K Q^T: d0 keys kv0+0..31, d1 keys kv0+32..63; lane owns q-col l31
    f32x16 d0 = {}, d1 = {};
    __builtin_amdgcn_s_setprio(1);
    #pragma unroll
    for (int s = 0; s < 8; ++s){
      const int cg = s*2 + hi;
      s16x8 kf0 = *reinterpret_cast<const s16x8*>(
          &Ks[cur][ l31*128      + ((cg ^ (l31 & 7)) << 3) ]);
      s16x8 kf1 = *reinterpret_cast<const s16x8*>(
          &Ks[cur][ (32+l31)*128 + ((cg ^ (l31 & 7)) << 3) ]);
      d0 = ATT_MFMA(kf0, qf[s], d0);
      d1 = ATT_MFMA(kf1, qf[s], d1);
    }
    __builtin_amdgcn_s_setprio(0);

    // two sequential 32-key online-softmax+PV updates; sm(d1) overlaps PV(d0) MFMA pipe
    half_update(d0, mA, &Vs[cur][0], 0 + hi, 2 + hi, mrun, lrun, o0, o1, o2, o3, l31, hi);
    half_update(d1, mB, &Vs[cur][0], 4 + hi, 6 + hi, mrun, lrun, o0, o1, o2, o3, l31, hi);

    __syncthreads();
    cur ^= 1;
  }

  // epilogue: O[q][dk] regs: col dk = dkblk*32 + l31, row q = (r&3)+8*(r>>2)+4*hi
  #pragma unroll
  for (int r = 0; r < 16; ++r){
    const int qs = (r & 3) + 8*(r >> 2) + 4*hi;
    const float lr = __shfl(lrun, qs);
    const float rl = (lr > 0.f) ? (1.f / lr) : 0.f;
    const int row = q0 + w*32 + qs;
    u16* cp = ctxb + (size_t)(b*NT + row) * ND + h*NDK + l31;
    cp[0]  = f2bf(o0[r] * rl);
    cp[32] = f2bf(o1[r] * rl);
    cp[64] = f2bf(o2[r] * rl);
    cp[96] = f2bf(o3[r] * rl);
  }
#undef STAGE
}

// ---------------------------------------------------------------- launcher
extern "C" void kernel_launch(void* const* d_in, const int* in_sizes, int n_in,
                              void* d_out, int out_size, void* d_ws, size_t ws_size,
                              hipStream_t stream) {
  const float* x      = (const float*)d_in[0];
  const float* mask   = (const float*)d_in[1];
  const float* Wqkv   = (const float*)d_in[2];
  const float* bqkv   = (const float*)d_in[3];
  const float* Wout   = (const float*)d_in[4];
  const float* bout   = (const float*)d_in[5];
  const float* fsmn_w = (const float*)d_in[6];
  float* out = (float*)d_out;

  // workspace layout (bytes); vT is written BY gemm<0> (which reads xb) -> no aliasing.
  char* ws = (char*)d_ws;
  u16* xb    = (u16*)ws;                         // 16,777,216
  u16* wqkvT = (u16*)(ws + 16777216);            //  1,572,864
  u16* woutT = (u16*)(ws + 18350080);            //    524,288
  u16* qkvb  = (u16*)(ws + 18874368);            // 50,331,648
  u16* ctxb  = (u16*)(ws + 69206016);            // 16,777,216
  u16* vT    = (u16*)(ws + 85983232);            // 16,777,216  (total ~103 MB)

  prep_kernel<<<2048, 256, 0, stream>>>(x, xb, Wqkv, wqkvT, Wout, woutT);
  gemm_bt<0><<<dim3(1536/128, 16384/128), 256, 0, stream>>>(
      xb, wqkvT, bqkv, qkvb, nullptr, vT, nullptr, nullptr, nullptr, NB*NT, QKV_LD, ND);
  attn_kernel<<<dim3(8, 64), 256, 0, stream>>>(qkvb, vT, mask, ctxb);
  gemm_bt<1><<<dim3(512/128, 16384/128), 256, 0, stream>>>(
      ctxb, woutT, bout, nullptr, out, nullptr, qkvb, mask, fsmn_w, NB*NT, ND, ND);
}

// Round 13
// 165.091 us; speedup vs baseline: 1.0990x; 1.0553x over previous
//
#include <hip/hip_runtime.h>
#include <hip/hip_bf16.h>
#include <stdint.h>

// Problem constants (from reference)
#define NB 8
#define NT 2048
#define ND 512
#define NH 4
#define NDK 128
#define QKV_LD 1536   // row stride of qkv buffer (3*D)
#define KW 11

typedef unsigned short u16;
typedef __attribute__((ext_vector_type(4))) float f32x4;
typedef __attribute__((ext_vector_type(16))) float f32x16;
typedef __attribute__((ext_vector_type(4))) float fv4;
typedef __attribute__((ext_vector_type(8))) short s16x8;   // 8 bf16 = 4 VGPR
typedef __attribute__((ext_vector_type(4))) unsigned short u16x4;
typedef __attribute__((ext_vector_type(4))) int i32x4;

#define AS1 __attribute__((address_space(1)))
#define AS3 __attribute__((address_space(3)))

__device__ __forceinline__ u16 f2bf(float f){
  unsigned u = __float_as_uint(f);
  u += 0x7fffu + ((u >> 16) & 1u);      // RNE
  return (u16)(u >> 16);
}
__device__ __forceinline__ float bf2f(u16 h){ return __uint_as_float(((unsigned)h) << 16); }
__device__ __forceinline__ unsigned pack2bf(float a, float b){
  float2 t; t.x = a; t.y = b;
  __hip_bfloat162 h = __float22bfloat162_rn(t);
  return *reinterpret_cast<unsigned*>(&h);
}

// ---------------------------------------------------------------- fused prep:
// blocks [0,1024): x -> bf16 (grid-stride)
// blocks [1024,1792): Wqkv transpose+cvt (512x1536 -> 1536x512)
// blocks [1792,2048): Wout transpose+cvt (512x512)
__device__ __forceinline__ void transpose_body(
    const float* __restrict__ in, u16* __restrict__ out, int R, int C,
    int bx, int by, int tid)
{
  __shared__ float tile[32][33];
  const int cb = bx * 32, rb = by * 32;
  const int tx = tid & 31, ty = tid >> 5;   // (32,8)
  #pragma unroll
  for (int i = 0; i < 4; ++i)
    tile[ty + i*8][tx] = in[(size_t)(rb + ty + i*8) * C + cb + tx];
  __syncthreads();
  #pragma unroll
  for (int i = 0; i < 4; ++i)
    out[(size_t)(cb + ty + i*8) * R + rb + tx] = f2bf(tile[tx][ty + i*8]);
}

__global__ void prep_kernel(const float* __restrict__ x, u16* __restrict__ xb,
                            const float* __restrict__ Wqkv, u16* __restrict__ wqkvT,
                            const float* __restrict__ Wout, u16* __restrict__ woutT)
{
  const int bid = blockIdx.x, tid = threadIdx.x;
  if (bid < 1024){
    const int n4 = (NB*NT*ND)/4;
    for (int i = bid*256 + tid; i < n4; i += 1024*256){
      float4 v = reinterpret_cast<const float4*>(x)[i];
      u16x4 o = { f2bf(v.x), f2bf(v.y), f2bf(v.z), f2bf(v.w) };
      reinterpret_cast<u16x4*>(xb)[i] = o;
    }
  } else if (bid < 1792){
    const int idx = bid - 1024;              // grid (48,16)
    transpose_body(Wqkv, wqkvT, 512, 1536, idx % 48, idx / 48, tid);
  } else {
    const int idx = bid - 1792;              // grid (16,16)
    transpose_body(Wout, woutT, 512, 512, idx % 16, idx / 16, tid);
  }
}

// ---------------------------------------------------------------- bf16 GEMM  C = A * Bt^T + bias
// BK=64 + XOR swizzle (rule #21): staging keeps LINEAR global_load_lds dest
// (chunk n -> row n>>3, col-chunk n&7); the global SOURCE col-chunk is pre-swizzled
// c^(row&7); frag reads use col-chunk (kk*4+g)^(r15&7) -> banks spread over all 32,
// 2-way residual (free, m136) instead of the 8-way conflict of the BK=32 layout.
// Barriers halve (8 K-iters x 2). LDS 32KB/block -> still 2 blocks/CU.
// EPI==0: C -> bf16; v-range blocks (n0 >= 2*ND) also write transposed V (vT).
// EPI==1: C -> f32 out with FUSED FSMN epilogue (taps read from qkvb, L2-resident;
//         OOB taps zeroed via mk=0, unguarded loads stay inside workspace).
template<int EPI>
__global__ __launch_bounds__(256, 2) void gemm_bt(
    const u16* __restrict__ A, const u16* __restrict__ Bt, const float* __restrict__ bias,
    u16* __restrict__ Cb, float* __restrict__ Cf, u16* __restrict__ vTout,
    const u16* __restrict__ qkvb, const float* __restrict__ mask,
    const float* __restrict__ fsmn_w,
    int M, int N, int Kd)
{
  __shared__ u16 As[128 * 64];
  __shared__ u16 Bs[128 * 64];
  const int tid = threadIdx.x;
  const int m0 = blockIdx.y * 128, n0 = blockIdx.x * 128;
  const int w = tid >> 6, l = tid & 63, wr = w >> 1, wc = w & 1;
  const int r15 = l & 15, g = l >> 4;

  f32x4 acc[4][4] = {};

  // staging: thread handles chunks n = i*256+tid, i=0..3; row = n>>3 = i*32 + (tid>>3),
  // col-chunk = tid&7 (same across i); source col-chunk swizzled by row&7 = (tid>>3)&7.
  const int r0 = tid >> 3;
  const int scol8 = ((tid & 7) ^ (r0 & 7)) << 3;   // u16 offset within the 64-col row
  const u16* Ag = A  + (size_t)(m0 + r0) * Kd + scol8;
  const u16* Bg = Bt + (size_t)(n0 + r0) * Kd + scol8;
  u16* Al = &As[(size_t)tid * 8];
  u16* Bl = &Bs[(size_t)tid * 8];

  for (int k0 = 0; k0 < Kd; k0 += 64){
    #pragma unroll
    for (int i = 0; i < 4; ++i)
      __builtin_amdgcn_global_load_lds((AS1 void*)(Ag + (size_t)(i*32) * Kd + k0),
                                       (AS3 void*)(Al + i*2048), 16, 0, 0);
    #pragma unroll
    for (int i = 0; i < 4; ++i)
      __builtin_amdgcn_global_load_lds((AS1 void*)(Bg + (size_t)(i*32) * Kd + k0),
                                       (AS3 void*)(Bl + i*2048), 16, 0, 0);
    __syncthreads();
    #pragma unroll
    for (int kk = 0; kk < 2; ++kk){
      s16x8 af[4], bfr[4];
      #pragma unroll
      for (int m = 0; m < 4; ++m){
        const int R = wr*64 + m*16 + r15;
        af[m] = *reinterpret_cast<const s16x8*>(
            &As[R*64 + (((kk*4 + g) ^ (r15 & 7)) << 3)]);
      }
      #pragma unroll
      for (int n = 0; n < 4; ++n){
        const int R = wc*64 + n*16 + r15;
        bfr[n] = *reinterpret_cast<const s16x8*>(
            &Bs[R*64 + (((kk*4 + g) ^ (r15 & 7)) << 3)]);
      }
      #pragma unroll
      for (int m = 0; m < 4; ++m){
        #pragma unroll
        for (int n = 0; n < 4; ++n)
          acc[m][n] = __builtin_amdgcn_mfma_f32_16x16x32_bf16(af[m], bfr[n], acc[m][n], 0, 0, 0);
      }
    }
    __syncthreads();
  }

  if (EPI == 0){
    const bool vrange = (n0 >= 2*ND);            // block-uniform (128-aligned ranges)
    #pragma unroll
    for (int m = 0; m < 4; ++m){
      const int gr0 = m0 + wr*64 + m*16 + g*4;
      #pragma unroll
      for (int n = 0; n < 4; ++n){
        const int gc = n0 + wc*64 + n*16 + r15;
        const float bv = bias[gc];
        u16x4 pk;
        #pragma unroll
        for (int j = 0; j < 4; ++j){
          const u16 hv = f2bf(acc[m][n][j] + bv);
          Cb[(size_t)(gr0 + j) * N + gc] = hv;
          pk[j] = hv;
        }
        if (vrange){                              // also write transposed V
          const int d  = gc - 2*ND;
          const int bh = (gr0 >> 11) * NH + (d >> 7);
          const int dk = d & 127, t = gr0 & 2047;
          *reinterpret_cast<u16x4*>(&vTout[((size_t)bh * NDK + dk) * NT + t]) = pk;
        }
      }
    }
  } else {
    // fused FSMN epilogue
    float wv[4][KW];
    #pragma unroll
    for (int n = 0; n < 4; ++n){
      const int gc = n0 + wc*64 + n*16 + r15;
      #pragma unroll
      for (int i = 0; i < KW; ++i) wv[n][i] = fsmn_w[gc*KW + i];
    }
    #pragma unroll
    for (int m = 0; m < 4; ++m){
      const int gr0 = m0 + wr*64 + m*16 + g*4;
      const int bb = gr0 >> 11, t0 = gr0 & 2047;
      const float* mb = mask + (size_t)bb * NT;
      float mk[14];
      #pragma unroll
      for (int i = 0; i < 14; ++i){
        const int tau = t0 - 5 + i;
        mk[i] = ((unsigned)tau < (unsigned)NT) ? mb[tau] : 0.f;
      }
      #pragma unroll
      for (int n = 0; n < 4; ++n){
        const int gc = n0 + wc*64 + n*16 + r15;
        const float bv = bias[gc];
        const u16* vb = qkvb + (size_t)bb * NT * QKV_LD + 2*ND + gc;
        float vmv[14];
        #pragma unroll
        for (int i = 0; i < 14; ++i){
          const ptrdiff_t tau = t0 - 5 + i;
          vmv[i] = mk[i] * bf2f(vb[tau * QKV_LD]);   // mk=0 zeroes OOB taps
        }
        #pragma unroll
        for (int j = 0; j < 4; ++j){
          float conv = vmv[5 + j];                    // vm[t] residual term
          #pragma unroll
          for (int i = 0; i < KW; ++i) conv = fmaf(wv[n][i], vmv[j + i], conv);
          Cf[(size_t)(gr0 + j) * N + gc] = acc[m][n][j] + bv + mk[5 + j] * conv;
        }
      }
    }
  }
}

// ---------------------------------------------------------------- flash attention (4-wave, 32x32x16)
// R10 structure (verified 110us; R12's half-split softmax regressed -> reverted).
// 256 thr = 4 waves x 32 q-rows; grid 512 = 2 independent blocks/CU (m114 overlap).
// Swapped QK^T: mfma(A=K, B=Q) -> lane owns ONE q-row, 32 scores in D regs.
// P->A-frag via 2x v_permlane32_swap_b32 per k-step. Single score set.
// DO NOT raise launch_bounds 2nd arg (R9: (256,3) -> 84 VGPR + scratch spill, 2.2x slower).
#define ATT_MFMA(a, bb, c) __builtin_amdgcn_mfma_f32_32x32x16_bf16(a, bb, c, 0, 0, 0)
#define C1F 0.12751741567f   /* (1/sqrt(128)) * log2(e) */

__global__ __launch_bounds__(256, 2) void attn_kernel(
    const u16* __restrict__ qkvb, const u16* __restrict__ vT,
    const float* __restrict__ mask, u16* __restrict__ ctxb)
{
  __shared__ u16 Ks[2][64 * 128];   // [key][dk], swizzled 16B chunks
  __shared__ u16 Vs[2][128 * 64];   // [dk][key], swizzled 16B chunks
  const int tid = threadIdx.x;
  const int w = tid >> 6, l = tid & 63, l31 = l & 31, hi = l >> 5;

  // XCD-bijective remap: all 16 q-blocks of one bh land on one XCD (K/V L2 locality)
  const int lin = blockIdx.x + blockIdx.y * 8;    // grid = (8, 64)
  const int xcd = lin & 7, jj = lin >> 3;         // jj 0..63
  const int bh = xcd * 4 + (jj & 3), qblk = jj >> 2;
  const int b = bh >> 2, h = bh & 3;
  const int q0 = qblk * 128;

  const u16* qptr = qkvb + (size_t)b * NT * QKV_LD + h * NDK;
  const u16* kb   = qptr + ND;
  const u16* vtb  = vT + (size_t)bh * NDK * NT;
  const float* mkp = mask + (size_t)b * NT;

  // Q in registers (B-operand): lane holds Q[q0+w*32+l31][s*16 + hi*8 .. +7]
  s16x8 qf[8];
  {
    const u16* qrow = qptr + (size_t)(q0 + w*32 + l31) * QKV_LD;
    #pragma unroll
    for (int s = 0; s < 8; ++s)
      qf[s] = *reinterpret_cast<const s16x8*>(qrow + s*16 + hi*8);
  }

  float mrun = -1e30f, lrun = 0.f;
  f32x16 o0 = {}, o1 = {}, o2 = {}, o3 = {};

  // K chunk c: key = c>>4, slot = c&15 (256B contiguous per key row, source XOR-swizzled).
  // V chunk c: dk = c>>3, kslot = c&7 (128B contiguous per dk row).
#define STAGE(buf, kvo) do { \
    _Pragma("unroll") \
    for (int i_ = 0; i_ < 4; ++i_){ \
      const int n_ = i_*256 + tid, kr_ = n_ >> 4, c_ = n_ & 15; \
      const u16* gp_ = kb + (size_t)((kvo) + kr_) * QKV_LD + ((c_ ^ (kr_ & 7)) << 3); \
      __builtin_amdgcn_global_load_lds((AS1 void*)gp_, (AS3 void*)&Ks[buf][n_*8], 16, 0, 0); \
    } \
    _Pragma("unroll") \
    for (int i_ = 0; i_ < 4; ++i_){ \
      const int n_ = i_*256 + tid, dr_ = n_ >> 3, kc_ = n_ & 7; \
      const u16* gp_ = vtb + (size_t)dr_ * NT + (kvo) + ((kc_ ^ (dr_ & 7)) << 3); \
      __builtin_amdgcn_global_load_lds((AS1 void*)gp_, (AS3 void*)&Vs[buf][n_*8], 16, 0, 0); \
    } \
  } while(0)

  STAGE(0, 0);
  __syncthreads();
  int cur = 0;

  for (int t = 0; t < NT/64; ++t){
    const int kv0 = t * 64;
    if (t + 1 < NT/64) STAGE(cur ^ 1, kv0 + 64);

    // mask for this tile: lane's k-locals are b32*32 + r8*8 + 4*hi + j
    fv4 mA[4], mB[4];
    #pragma unroll
    for (int r8 = 0; r8 < 4; ++r8){
      mA[r8] = *reinterpret_cast<const fv4*>(&mkp[kv0      + r8*8 + hi*4]);
      mB[r8] = *reinterpret_cast<const fv4*>(&mkp[kv0 + 32 + r8*8 + hi*4]);
    }

    // S^T = K Q^T: d0 keys kv0+0..31, d1 keys kv0+32..63; lane owns q-col l31
    f32x16 d0 = {}, d1 = {};
    __builtin_amdgcn_s_setprio(1);
    #pragma unroll
    for (int s = 0; s < 8; ++s){
      const int cg = s*2 + hi;
      s16x8 kf0 = *reinterpret_cast<const s16x8*>(
          &Ks[cur][ l31*128      + ((cg ^ (l31 & 7)) << 3) ]);
      s16x8 kf1 = *reinterpret_cast<const s16x8*>(
          &Ks[cur][ (32+l31)*128 + ((cg ^ (l31 & 7)) << 3) ]);
      d0 = ATT_MFMA(kf0, qf[s], d0);
      d1 = ATT_MFMA(kf1, qf[s], d1);
    }
    __builtin_amdgcn_s_setprio(0);

    // row max over raw scores: max3-friendly tree, then cross-half
    float mx0 = fmaxf(d0[0], d0[1]), mx1 = fmaxf(d0[2], d0[3]);
    float mx2 = fmaxf(d1[0], d1[1]), mx3 = fmaxf(d1[2], d1[3]);
    #pragma unroll
    for (int r = 4; r < 16; r += 4){
      mx0 = fmaxf(mx0, fmaxf(d0[r],   d0[r+1]));
      mx1 = fmaxf(mx1, fmaxf(d0[r+2], d0[r+3]));
      mx2 = fmaxf(mx2, fmaxf(d1[r],   d1[r+1]));
      mx3 = fmaxf(mx3, fmaxf(d1[r+2], d1[r+3]));
    }
    float tmx = fmaxf(fmaxf(mx0, mx1), fmaxf(mx2, mx3));
    tmx = fmaxf(tmx, __shfl_xor(tmx, 32));

    // T13 defer-max (raw-score threshold 64 ~ 8 nats)
    if (!__all(tmx <= mrun + 64.f)){
      const float mn = fmaxf(mrun, tmx);
      const float corr = __builtin_amdgcn_exp2f((mrun - mn) * C1F);
      mrun = mn; lrun *= corr;
      #pragma unroll
      for (int r = 0; r < 16; ++r){
        const int qs = (r & 3) + 8*(r >> 2) + 4*hi;
        const float cq = __shfl(corr, qs);
        o0[r] *= cq; o1[r] *= cq; o2[r] *= cq; o3[r] *= cq;
      }
    }

    // p = exp2(fma(s, c1, -m*c1)) * mask; in-place into d0/d1; accumulate l
    const float mm = mrun * C1F;
    float ts = 0.f;
    #pragma unroll
    for (int r = 0; r < 16; ++r){
      const int r8 = r >> 2, j = r & 3;
      const float p0 = __builtin_amdgcn_exp2f(fmaf(d0[r], C1F, -mm)) * mA[r8][j];
      const float p1 = __builtin_amdgcn_exp2f(fmaf(d1[r], C1F, -mm)) * mB[r8][j];
      d0[r] = p0; d1[r] = p1; ts += p0 + p1;
    }
    ts += __shfl_xor(ts, 32);
    lrun += ts;

    // pack p -> bf16 pairs
    unsigned pku[2][4][2];
    #pragma unroll
    for (int r8 = 0; r8 < 4; ++r8){
      pku[0][r8][0] = pack2bf(d0[4*r8+0], d0[4*r8+1]);
      pku[0][r8][1] = pack2bf(d0[4*r8+2], d0[4*r8+3]);
      pku[1][r8][0] = pack2bf(d1[4*r8+0], d1[4*r8+1]);
      pku[1][r8][1] = pack2bf(d1[4*r8+2], d1[4*r8+3]);
    }

    // PV: per k-step build A-frag with 2 permlane32_swap, then 4 dk-blocks
    #pragma unroll
    for (int ks = 0; ks < 4; ++ks){
      const int bb = ks >> 1, rlo = (ks & 1) * 2;
      int u0 = (int)pku[bb][rlo][0],   u1 = (int)pku[bb][rlo][1];
      int v0 = (int)pku[bb][rlo+1][0], v1 = (int)pku[bb][rlo+1][1];
      asm("v_permlane32_swap_b32 %0, %1" : "+v"(u0), "+v"(v0));
      asm("v_permlane32_swap_b32 %0, %1" : "+v"(u1), "+v"(v1));
      union { i32x4 i; s16x8 hv; } pu;
      pu.i[0] = u0; pu.i[1] = u1; pu.i[2] = v0; pu.i[3] = v1;
      const int cg = ks*2 + hi;
      s16x8 vf0 = *reinterpret_cast<const s16x8*>(&Vs[cur][ (l31     )*64 + ((cg ^ (l31 & 7)) << 3) ]);
      s16x8 vf1 = *reinterpret_cast<const s16x8*>(&Vs[cur][ (32 + l31)*64 + ((cg ^ (l31 & 7)) << 3) ]);
      s16x8 vf2 = *reinterpret_cast<const s16x8*>(&Vs[cur][ (64 + l31)*64 + ((cg ^ (l31 & 7)) << 3) ]);
      s16x8 vf3 = *reinterpret_cast<const s16x8*>(&Vs[cur][ (96 + l31)*64 + ((cg ^ (l31 & 7)) << 3) ]);
      __builtin_amdgcn_s_setprio(1);
      o0 = ATT_MFMA(pu.hv, vf0, o0);
      o1 = ATT_MFMA(pu.hv, vf1, o1);
      o2 = ATT_MFMA(pu.hv, vf2, o2);
      o3 = ATT_MFMA(pu.hv, vf3, o3);
      __builtin_amdgcn_s_setprio(0);
    }

    __syncthreads();
    cur ^= 1;
  }

  // epilogue: O[q][dk] regs: col dk = dkblk*32 + l31, row q = (r&3)+8*(r>>2)+4*hi
  #pragma unroll
  for (int r = 0; r < 16; ++r){
    const int qs = (r & 3) + 8*(r >> 2) + 4*hi;
    const float lr = __shfl(lrun, qs);
    const float rl = (lr > 0.f) ? (1.f / lr) : 0.f;
    const int row = q0 + w*32 + qs;
    u16* cp = ctxb + (size_t)(b*NT + row) * ND + h*NDK + l31;
    cp[0]  = f2bf(o0[r] * rl);
    cp[32] = f2bf(o1[r] * rl);
    cp[64] = f2bf(o2[r] * rl);
    cp[96] = f2bf(o3[r] * rl);
  }
#undef STAGE
}

// ---------------------------------------------------------------- launcher
extern "C" void kernel_launch(void* const* d_in, const int* in_sizes, int n_in,
                              void* d_out, int out_size, void* d_ws, size_t ws_size,
                              hipStream_t stream) {
  const float* x      = (const float*)d_in[0];
  const float* mask   = (const float*)d_in[1];
  const float* Wqkv   = (const float*)d_in[2];
  const float* bqkv   = (const float*)d_in[3];
  const float* Wout   = (const float*)d_in[4];
  const float* bout   = (const float*)d_in[5];
  const float* fsmn_w = (const float*)d_in[6];
  float* out = (float*)d_out;

  // workspace layout (bytes); vT is written BY gemm<0> (which reads xb) -> no aliasing.
  char* ws = (char*)d_ws;
  u16* xb    = (u16*)ws;                         // 16,777,216
  u16* wqkvT = (u16*)(ws + 16777216);            //  1,572,864
  u16* woutT = (u16*)(ws + 18350080);            //    524,288
  u16* qkvb  = (u16*)(ws + 18874368);            // 50,331,648
  u16* ctxb  = (u16*)(ws + 69206016);            // 16,777,216
  u16* vT    = (u16*)(ws + 85983232);            // 16,777,216  (total ~103 MB)

  prep_kernel<<<2048, 256, 0, stream>>>(x, xb, Wqkv, wqkvT, Wout, woutT);
  gemm_bt<0><<<dim3(1536/128, 16384/128), 256, 0, stream>>>(
      xb, wqkvT, bqkv, qkvb, nullptr, vT, nullptr, nullptr, nullptr, NB*NT, QKV_LD, ND);
  attn_kernel<<<dim3(8, 64), 256, 0, stream>>>(qkvb, vT, mask, ctxb);
  gemm_bt<1><<<dim3(512/128, 16384/128), 256, 0, stream>>>(
      ctxb, woutT, bout, nullptr, out, nullptr, qkvb, mask, fsmn_w, NB*NT, ND, ND);
}